// Round 1
// baseline (59.219 us; speedup 1.0000x reference)
//
#include <hip/hip_runtime.h>
#include <hip/hip_bf16.h>

#define NUM_OPS 8
#define D 1024
#define B_ROWS 8192

typedef unsigned short ushort_t;
typedef __attribute__((ext_vector_type(8))) short bf16x8;
typedef __attribute__((ext_vector_type(4))) float f32x4;
typedef __attribute__((ext_vector_type(4))) float float4v;
typedef __attribute__((ext_vector_type(8))) unsigned short ushort8;

__device__ __forceinline__ unsigned short f2bf(float f) {
    union { float f; unsigned int u; } v; v.f = f;
    unsigned int u = v.u;
    unsigned int lsb = (u >> 16) & 1u;
    u += 0x7fffu + lsb;   // round-to-nearest-even
    return (unsigned short)(u >> 16);
}

__device__ __forceinline__ void load_lds16(const void* g, void* l) {
    __builtin_amdgcn_global_load_lds(
        (const __attribute__((address_space(1))) void*)g,
        (__attribute__((address_space(3))) void*)l,
        16, 0, 0);
}

// ---------------- top-2 selection ----------------
__global__ void topk_kernel(const float* __restrict__ logits, int* __restrict__ idx) {
    if (threadIdx.x == 0 && blockIdx.x == 0) {
        float best = -__builtin_inff(); int bi = 0;
        for (int i = 0; i < NUM_OPS; ++i) {
            float v = logits[i];
            if (v > best) { best = v; bi = i; }
        }
        float best2 = -__builtin_inff(); int bi2 = 0;
        for (int i = 0; i < NUM_OPS; ++i) {
            if (i == bi) continue;
            float v = logits[i];
            if (v > best2) { best2 = v; bi2 = i; }
        }
        idx[0] = bi; idx[1] = bi2;
    }
}

// ---------------- x : f32 -> bf16 ----------------
__global__ void convert_x(const float* __restrict__ x, ushort_t* __restrict__ xb) {
    int i = (blockIdx.x * 256 + threadIdx.x) * 8;
    float4v v0 = *(const float4v*)(x + i);
    float4v v1 = *(const float4v*)(x + i + 4);
    ushort8 o;
    o[0] = f2bf(v0[0]); o[1] = f2bf(v0[1]); o[2] = f2bf(v0[2]); o[3] = f2bf(v0[3]);
    o[4] = f2bf(v1[0]); o[5] = f2bf(v1[1]); o[6] = f2bf(v1[2]); o[7] = f2bf(v1[3]);
    *(ushort8*)(xb + i) = o;
}

// ------- gather selected experts' W, transpose to [n][k], cast bf16 -------
// Wt[e][n*D + k] = (bf16) Ws[idx[e]][k*D + n]
__global__ void gather_transpose_W(const float* __restrict__ Ws,
                                   const int* __restrict__ idx,
                                   ushort_t* __restrict__ Wt) {
    __shared__ float t[32][33];
    int e    = blockIdx.x >> 10;        // 2 experts x 1024 tiles
    int tile = blockIdx.x & 1023;
    int td = (tile >> 5) << 5;          // k (input-dim) tile base
    int te = (tile & 31) << 5;          // n (output-dim) tile base
    int tx = threadIdx.x & 31, ty = threadIdx.x >> 5;   // 32x8
    const float* W = Ws + (size_t)idx[e] * D * D;
    for (int r = 0; r < 4; ++r)
        t[ty + 8 * r][tx] = W[(size_t)(td + ty + 8 * r) * D + te + tx];
    __syncthreads();
    ushort_t* o = Wt + (size_t)e * D * D;
    for (int r = 0; r < 4; ++r)
        o[(size_t)(te + ty + 8 * r) * D + td + tx] = f2bf(t[tx][ty + 8 * r]);
}

// ---------------- fused dual-expert GEMM ----------------
// out[m][n] = relu(A·W0 + b0)[m][n] + relu(A·W1 + b1)[m][n]
// A: [8192][1024] bf16 row-major. Wt[e]: [n][k] bf16 (transposed).
__global__ __launch_bounds__(256, 2)
void gemm_dual(const ushort_t* __restrict__ Abf, const ushort_t* __restrict__ Wt,
               const float* __restrict__ bs, const int* __restrict__ idx,
               float* __restrict__ out) {
    constexpr int BM = 128, BN = 128, BK = 64;
    __shared__ __align__(16) ushort_t As[BM * BK];        // [128][64]
    __shared__ __align__(16) ushort_t Bs[2][BN * BK];     // [128][64] each

    const int tid  = threadIdx.x;
    const int wv   = tid >> 6;
    const int lane = tid & 63;
    const int wr   = wv >> 1, wc = wv & 1;
    const int brow = blockIdx.x * BM;
    const int bcol = blockIdx.y * BN;

    f32x4 acc[2][4][4] = {};

    const ushort_t* B0 = Wt;
    const ushort_t* B1 = Wt + (size_t)D * D;

    for (int t = 0; t < D / BK; ++t) {
        __syncthreads();   // previous compute done before LDS overwrite
        // stage A tile + both B tiles: 16KB each tile in 4 wave-iterations
        for (int it = 0; it < 4; ++it) {
            int c   = it * 256 + tid;
            int row = c >> 3, ch = c & 7;
            const ushort_t* gA  = Abf + (size_t)(brow + row) * D + t * BK + ch * 8;
            const ushort_t* gB0 = B0  + (size_t)(bcol + row) * D + t * BK + ch * 8;
            const ushort_t* gB1 = B1  + (size_t)(bcol + row) * D + t * BK + ch * 8;
            ushort_t* lA  = As    + (it * 4 + wv) * 512;   // 1 KB per wave per iter
            ushort_t* lB0 = Bs[0] + (it * 4 + wv) * 512;
            ushort_t* lB1 = Bs[1] + (it * 4 + wv) * 512;
            load_lds16(gA,  lA);
            load_lds16(gB0, lB0);
            load_lds16(gB1, lB1);
        }
        __syncthreads();   // (compiler drains vmcnt before barrier)

        // compute on staged tiles
        for (int kk = 0; kk < 2; ++kk) {
            bf16x8 a[4], b[2][4];
            const int lrow = lane & 15;
            const int lk   = kk * 32 + ((lane >> 4) << 3);
            #pragma unroll
            for (int m = 0; m < 4; ++m)
                a[m] = *(const bf16x8*)&As[(wr * 64 + m * 16 + lrow) * BK + lk];
            #pragma unroll
            for (int e = 0; e < 2; ++e)
                #pragma unroll
                for (int n = 0; n < 4; ++n)
                    b[e][n] = *(const bf16x8*)&Bs[e][(wc * 64 + n * 16 + lrow) * BK + lk];
            #pragma unroll
            for (int e = 0; e < 2; ++e)
                #pragma unroll
                for (int m = 0; m < 4; ++m)
                    #pragma unroll
                    for (int n = 0; n < 4; ++n)
                        acc[e][m][n] = __builtin_amdgcn_mfma_f32_16x16x32_bf16(
                            a[m], b[e][n], acc[e][m][n], 0, 0, 0);
        }
    }

    // epilogue: bias + relu per expert, then sum
    const int i0 = idx[0], i1 = idx[1];
    const int lcol = lane & 15, lrow4 = (lane >> 4) * 4;
    #pragma unroll
    for (int n = 0; n < 4; ++n) {
        int col = bcol + wc * 64 + n * 16 + lcol;
        float bias0 = bs[i0 * D + col];
        float bias1 = bs[i1 * D + col];
        #pragma unroll
        for (int m = 0; m < 4; ++m) {
            int rbase = brow + wr * 64 + m * 16 + lrow4;
            #pragma unroll
            for (int i = 0; i < 4; ++i) {
                float v0 = acc[0][m][n][i] + bias0; v0 = v0 > 0.f ? v0 : 0.f;
                float v1 = acc[1][m][n][i] + bias1; v1 = v1 > 0.f ? v1 : 0.f;
                out[(size_t)(rbase + i) * D + col] = v0 + v1;
            }
        }
    }
}

extern "C" void kernel_launch(void* const* d_in, const int* in_sizes, int n_in,
                              void* d_out, int out_size, void* d_ws, size_t ws_size,
                              hipStream_t stream) {
    const float* x      = (const float*)d_in[0];
    const float* logits = (const float*)d_in[1];
    const float* Ws     = (const float*)d_in[2];
    const float* bs     = (const float*)d_in[3];
    float* out = (float*)d_out;

    char* ws = (char*)d_ws;
    ushort_t* xbf = (ushort_t*)ws;                                   // 16 MB
    ushort_t* Wt  = (ushort_t*)(ws + (size_t)B_ROWS * D * 2);        //  4 MB
    int* idx      = (int*)(ws + (size_t)B_ROWS * D * 2 + (size_t)2 * D * D * 2);

    topk_kernel<<<1, 1, 0, stream>>>(logits, idx);
    convert_x<<<(B_ROWS * D) / (256 * 8), 256, 0, stream>>>(x, xbf);
    gather_transpose_W<<<2 * (D / 32) * (D / 32), 256, 0, stream>>>(Ws, idx, Wt);

    dim3 grid(B_ROWS / 128, D / 128);
    gemm_dual<<<grid, 256, 0, stream>>>(xbf, Wt, bs, idx, out);
}

// Round 2
// 58.657 us; speedup vs baseline: 1.0096x; 1.0096x over previous
//
#include <hip/hip_runtime.h>
#include <hip/hip_bf16.h>

#define NUM_OPS 8
#define D 1024
#define B_ROWS 8192

typedef unsigned short ushort_t;
typedef __attribute__((ext_vector_type(8))) short bf16x8;
typedef __attribute__((ext_vector_type(4))) float f32x4;
typedef __attribute__((ext_vector_type(4))) float float4v;
typedef __attribute__((ext_vector_type(8))) unsigned short ushort8;

__device__ __forceinline__ unsigned short f2bf(float f) {
    union { float f; unsigned int u; } v; v.f = f;
    unsigned int u = v.u;
    unsigned int lsb = (u >> 16) & 1u;
    u += 0x7fffu + lsb;   // round-to-nearest-even
    return (unsigned short)(u >> 16);
}

__device__ __forceinline__ void load_lds16(const void* g, void* l) {
    __builtin_amdgcn_global_load_lds(
        (const __attribute__((address_space(1))) void*)g,
        (__attribute__((address_space(3))) void*)l,
        16, 0, 0);
}

// ---------------- top-2 selection ----------------
__global__ void topk_kernel(const float* __restrict__ logits, int* __restrict__ idx) {
    if (threadIdx.x == 0 && blockIdx.x == 0) {
        float best = -__builtin_inff(); int bi = 0;
        for (int i = 0; i < NUM_OPS; ++i) {
            float v = logits[i];
            if (v > best) { best = v; bi = i; }
        }
        float best2 = -__builtin_inff(); int bi2 = 0;
        for (int i = 0; i < NUM_OPS; ++i) {
            if (i == bi) continue;
            float v = logits[i];
            if (v > best2) { best2 = v; bi2 = i; }
        }
        idx[0] = bi; idx[1] = bi2;
    }
}

// ---------------- x : f32 -> bf16 ----------------
__global__ void convert_x(const float* __restrict__ x, ushort_t* __restrict__ xb) {
    int i = (blockIdx.x * 256 + threadIdx.x) * 8;
    float4v v0 = *(const float4v*)(x + i);
    float4v v1 = *(const float4v*)(x + i + 4);
    ushort8 o;
    o[0] = f2bf(v0[0]); o[1] = f2bf(v0[1]); o[2] = f2bf(v0[2]); o[3] = f2bf(v0[3]);
    o[4] = f2bf(v1[0]); o[5] = f2bf(v1[1]); o[6] = f2bf(v1[2]); o[7] = f2bf(v1[3]);
    *(ushort8*)(xb + i) = o;
}

// ------- gather selected experts' W, transpose to [n][k], cast bf16 -------
// Wt[e][n*D + k] = (bf16) Ws[idx[e]][k*D + n]
__global__ void gather_transpose_W(const float* __restrict__ Ws,
                                   const int* __restrict__ idx,
                                   ushort_t* __restrict__ Wt) {
    __shared__ float t[32][33];
    int e    = blockIdx.x >> 10;
    int tile = blockIdx.x & 1023;
    int td = (tile >> 5) << 5;
    int te = (tile & 31) << 5;
    int tx = threadIdx.x & 31, ty = threadIdx.x >> 5;
    const float* W = Ws + (size_t)idx[e] * D * D;
    for (int r = 0; r < 4; ++r)
        t[ty + 8 * r][tx] = W[(size_t)(td + ty + 8 * r) * D + te + tx];
    __syncthreads();
    ushort_t* o = Wt + (size_t)e * D * D;
    for (int r = 0; r < 4; ++r)
        o[(size_t)(te + ty + 8 * r) * D + td + tx] = f2bf(t[tx][ty + 8 * r]);
}

// ---------------- staging helpers (linear LDS dest, inverse-swizzled src) --
// LDS tile layout: [256 rows][64 cols] bf16, row stride 128B.
// swizzle: LDS byte (r*128 + c') holds global byte-col (c' ^ ((r&7)<<4)).
__device__ __forceinline__ void stage_half_A(const ushort_t* __restrict__ Abf,
                                             int brow, int t, ushort_t* dstbuf,
                                             int h, int tid, int wv) {
    #pragma unroll
    for (int i = 0; i < 2; ++i) {
        const int c   = i * 512 + tid;
        const int rr  = c >> 3;                 // 0..127 row within half
        const int cb  = (c & 7) * 16;           // byte col of LDS slot
        const int gcb = cb ^ ((rr & 7) << 4);   // inverse-swizzled global byte col
        const ushort_t* g = Abf + (size_t)(brow + h * 128 + rr) * D + t * 64 + (gcb >> 1);
        ushort_t* l = dstbuf + (h * 16384 + (i * 512 + wv * 64) * 16) / 2;  // wave-uniform
        load_lds16(g, l);
    }
}

__device__ __forceinline__ void stage_half_B(const ushort_t* __restrict__ Wt,
                                             int bcolIdx, int t, ushort_t* dstbuf,
                                             int h, int tid, int wv) {
    #pragma unroll
    for (int i = 0; i < 2; ++i) {
        const int c   = i * 512 + tid;
        const int rr  = c >> 3;                 // col-within-expert 0..127
        const int cb  = (c & 7) * 16;
        const int gcb = cb ^ ((rr & 7) << 4);
        const ushort_t* g = Wt + (size_t)h * D * D
                          + (size_t)(bcolIdx * 128 + rr) * D + t * 64 + (gcb >> 1);
        ushort_t* l = dstbuf + (h * 16384 + (i * 512 + wv * 64) * 16) / 2;
        load_lds16(g, l);
    }
}

#define BAR()   do { __builtin_amdgcn_s_barrier(); __builtin_amdgcn_sched_barrier(0); } while (0)
#define LGKM0() do { asm volatile("s_waitcnt lgkmcnt(0)" ::: "memory"); __builtin_amdgcn_sched_barrier(0); } while (0)
#define VM(N)   do { asm volatile("s_waitcnt vmcnt(" #N ")" ::: "memory"); __builtin_amdgcn_sched_barrier(0); } while (0)
#define PRIO1() __builtin_amdgcn_s_setprio(1)
#define PRIO0() __builtin_amdgcn_s_setprio(0)

// ds_read fragments (swizzled addresses)
#define DS_A(mh)                                                                   \
    do {                                                                           \
        _Pragma("unroll") for (int kk = 0; kk < 2; ++kk)                           \
        _Pragma("unroll") for (int m = 0; m < 4; ++m)                              \
            af[kk][m] = *(const bf16x8*)(curA +                                    \
                (size_t)((wr * 128 + (mh) * 64 + m * 16 + l15) * 128) +            \
                (kk ? x1 : x0));                                                   \
    } while (0)

#define DS_B(E)                                                                    \
    do {                                                                           \
        _Pragma("unroll") for (int kk = 0; kk < 2; ++kk)                           \
        _Pragma("unroll") for (int n = 0; n < 2; ++n)                              \
            bfr[E][kk][n] = *(const bf16x8*)(curB +                                \
                (size_t)(((E) * 128 + wc * 32 + n * 16 + l15) * 128) +             \
                (kk ? x1 : x0));                                                   \
    } while (0)

#define MM(E, mh)                                                                  \
    do {                                                                           \
        _Pragma("unroll") for (int kk = 0; kk < 2; ++kk)                           \
        _Pragma("unroll") for (int m = 0; m < 4; ++m)                              \
        _Pragma("unroll") for (int n = 0; n < 2; ++n)                              \
            acc[E][(mh) * 4 + m][n] = __builtin_amdgcn_mfma_f32_16x16x32_bf16(     \
                af[kk][m], bfr[E][kk][n], acc[E][(mh) * 4 + m][n], 0, 0, 0);       \
    } while (0)

// ---------------- fused dual-expert GEMM, 256-row 8-phase pipeline ----------
// Block: 256 rows x 128 out-cols x 2 experts. 8 waves = 2M x 4N.
// Wave tile: 128 rows x 32 cols x 2 experts. BK=64.
__global__ __launch_bounds__(512, 2)
void gemm_dual(const ushort_t* __restrict__ Abf, const ushort_t* __restrict__ Wt,
               const float* __restrict__ bs, const int* __restrict__ idx,
               float* __restrict__ out) {
    constexpr int NT = D / 64;   // 16 K-tiles
    __shared__ __align__(16) ushort_t ldsA[2][256 * 64];   // 64 KB
    __shared__ __align__(16) ushort_t ldsB[2][256 * 64];   // 64 KB

    const int tid  = threadIdx.x;
    const int wv   = tid >> 6;
    const int lane = tid & 63;
    const int wr   = wv >> 2, wc = wv & 3;
    const int l15  = lane & 15, lq = lane >> 4;
    const int swz  = (lane & 7) << 4;
    const int x0   = (lq * 16) ^ swz;          // kk=0 swizzled byte col
    const int x1   = (64 + lq * 16) ^ swz;     // kk=1

    // XCD-chunked swizzle: each XCD (bid&7) owns one 128-col panel, all 32 row-blocks
    const int bid     = blockIdx.x;
    const int brow    = (bid >> 3) * 256;
    const int bcolIdx = bid & 7;

    f32x4  acc[2][8][2] = {};
    bf16x8 af[2][4];        // [kk][m within mh]
    bf16x8 bfr[2][2][2];    // [e][kk][n]

    // prologue: stage tile 0 into buffer 0
    stage_half_A(Abf, brow, 0, ldsA[0], 0, tid, wv);
    stage_half_A(Abf, brow, 0, ldsA[0], 1, tid, wv);
    stage_half_B(Wt, bcolIdx, 0, ldsB[0], 0, tid, wv);
    stage_half_B(Wt, bcolIdx, 0, ldsB[0], 1, tid, wv);
    VM(0);
    BAR();

    for (int t = 0; t < NT - 1; ++t) {
        const char* curA = (const char*)ldsA[t & 1];
        const char* curB = (const char*)ldsB[t & 1];
        ushort_t* nA = ldsA[(t & 1) ^ 1];
        ushort_t* nB = ldsB[(t & 1) ^ 1];

        // ---- phase 1: quadrant (mh=0, e=0); stage Ah0 of t+1
        DS_A(0); DS_B(0);
        stage_half_A(Abf, brow, t + 1, nA, 0, tid, wv);
        BAR(); LGKM0();
        PRIO1(); MM(0, 0); PRIO0();
        VM(2);          // drain prev tile's Bh1 before ph2 reads expert-1 B
        BAR();

        // ---- phase 2: quadrant (mh=0, e=1); stage Ah1
        DS_B(1);
        stage_half_A(Abf, brow, t + 1, nA, 1, tid, wv);
        BAR(); LGKM0();
        PRIO1(); MM(1, 0); PRIO0();
        BAR();

        // ---- phase 3: quadrant (mh=1, e=1); stage Bh0
        DS_A(1);
        stage_half_B(Wt, bcolIdx, t + 1, nB, 0, tid, wv);
        BAR(); LGKM0();
        PRIO1(); MM(1, 1); PRIO0();
        BAR();

        // ---- phase 4: quadrant (mh=1, e=0); stage Bh1
        stage_half_B(Wt, bcolIdx, t + 1, nB, 1, tid, wv);
        BAR(); LGKM0();
        PRIO1(); MM(0, 1); PRIO0();
        VM(2);          // Ah0/Ah1/Bh0 of t+1 landed; Bh1 may stay in flight
        BAR();
    }

    // ---- last tile (t = NT-1), no staging
    {
        const char* curA = (const char*)ldsA[(NT - 1) & 1];
        const char* curB = (const char*)ldsB[(NT - 1) & 1];

        DS_A(0); DS_B(0);
        BAR(); LGKM0();
        PRIO1(); MM(0, 0); PRIO0();
        VM(0);          // drain this tile's Bh1
        BAR();

        DS_B(1);
        BAR(); LGKM0();
        PRIO1(); MM(1, 0); PRIO0();
        BAR();

        DS_A(1);
        BAR(); LGKM0();
        PRIO1(); MM(1, 1); PRIO0();
        BAR();

        LGKM0();
        PRIO1(); MM(0, 1); PRIO0();
    }

    // ---- epilogue: per-expert bias + relu, sum, store f32
    const int i0 = idx[0], i1 = idx[1];
    #pragma unroll
    for (int n = 0; n < 2; ++n) {
        const int col = bcolIdx * 128 + wc * 32 + n * 16 + l15;
        const float b0 = bs[i0 * D + col];
        const float b1 = bs[i1 * D + col];
        #pragma unroll
        for (int m = 0; m < 8; ++m) {
            const int rbase = brow + wr * 128 + m * 16 + lq * 4;
            #pragma unroll
            for (int i = 0; i < 4; ++i) {
                float v0 = acc[0][m][n][i] + b0; v0 = v0 > 0.f ? v0 : 0.f;
                float v1 = acc[1][m][n][i] + b1; v1 = v1 > 0.f ? v1 : 0.f;
                out[(size_t)(rbase + i) * D + col] = v0 + v1;
            }
        }
    }
}

extern "C" void kernel_launch(void* const* d_in, const int* in_sizes, int n_in,
                              void* d_out, int out_size, void* d_ws, size_t ws_size,
                              hipStream_t stream) {
    const float* x      = (const float*)d_in[0];
    const float* logits = (const float*)d_in[1];
    const float* Ws     = (const float*)d_in[2];
    const float* bs     = (const float*)d_in[3];
    float* out = (float*)d_out;

    char* ws = (char*)d_ws;
    ushort_t* xbf = (ushort_t*)ws;                                   // 16 MB
    ushort_t* Wt  = (ushort_t*)(ws + (size_t)B_ROWS * D * 2);        //  4 MB
    int* idx      = (int*)(ws + (size_t)B_ROWS * D * 2 + (size_t)2 * D * D * 2);

    topk_kernel<<<1, 1, 0, stream>>>(logits, idx);
    convert_x<<<(B_ROWS * D) / (256 * 8), 256, 0, stream>>>(x, xbf);
    gather_transpose_W<<<2 * (D / 32) * (D / 32), 256, 0, stream>>>(Ws, idx, Wt);

    gemm_dual<<<256, 512, 0, stream>>>(xbf, Wt, bs, idx, out);
}

// Round 3
// 58.272 us; speedup vs baseline: 1.0162x; 1.0066x over previous
//
#include <hip/hip_runtime.h>
#include <hip/hip_bf16.h>

#define NUM_OPS 8
#define D 1024
#define B_ROWS 8192

typedef unsigned short ushort_t;
typedef __attribute__((ext_vector_type(8))) short bf16x8;
typedef __attribute__((ext_vector_type(4))) float f32x4;
typedef __attribute__((ext_vector_type(4))) float float4v;
typedef __attribute__((ext_vector_type(8))) unsigned short ushort8;

__device__ __forceinline__ unsigned short f2bf(float f) {
    union { float f; unsigned int u; } v; v.f = f;
    unsigned int u = v.u;
    unsigned int lsb = (u >> 16) & 1u;
    u += 0x7fffu + lsb;   // round-to-nearest-even
    return (unsigned short)(u >> 16);
}

__device__ __forceinline__ void load_lds16(const void* g, void* l) {
    __builtin_amdgcn_global_load_lds(
        (const __attribute__((address_space(1))) void*)g,
        (__attribute__((address_space(3))) void*)l,
        16, 0, 0);
}

// ---------------- top-2 selection ----------------
__global__ void topk_kernel(const float* __restrict__ logits, int* __restrict__ idx) {
    if (threadIdx.x == 0 && blockIdx.x == 0) {
        float best = -__builtin_inff(); int bi = 0;
        for (int i = 0; i < NUM_OPS; ++i) {
            float v = logits[i];
            if (v > best) { best = v; bi = i; }
        }
        float best2 = -__builtin_inff(); int bi2 = 0;
        for (int i = 0; i < NUM_OPS; ++i) {
            if (i == bi) continue;
            float v = logits[i];
            if (v > best2) { best2 = v; bi2 = i; }
        }
        idx[0] = bi; idx[1] = bi2;
    }
}

// ---------------- x : f32 -> bf16 ----------------
__global__ void convert_x(const float* __restrict__ x, ushort_t* __restrict__ xb) {
    int i = (blockIdx.x * 256 + threadIdx.x) * 8;
    float4v v0 = *(const float4v*)(x + i);
    float4v v1 = *(const float4v*)(x + i + 4);
    ushort8 o;
    o[0] = f2bf(v0[0]); o[1] = f2bf(v0[1]); o[2] = f2bf(v0[2]); o[3] = f2bf(v0[3]);
    o[4] = f2bf(v1[0]); o[5] = f2bf(v1[1]); o[6] = f2bf(v1[2]); o[7] = f2bf(v1[3]);
    *(ushort8*)(xb + i) = o;
}

// ------- gather selected experts' W, transpose to [n][k], cast bf16 -------
__global__ void gather_transpose_W(const float* __restrict__ Ws,
                                   const int* __restrict__ idx,
                                   ushort_t* __restrict__ Wt) {
    __shared__ float t[32][33];
    int e    = blockIdx.x >> 10;
    int tile = blockIdx.x & 1023;
    int td = (tile >> 5) << 5;
    int te = (tile & 31) << 5;
    int tx = threadIdx.x & 31, ty = threadIdx.x >> 5;
    const float* W = Ws + (size_t)idx[e] * D * D;
    for (int r = 0; r < 4; ++r)
        t[ty + 8 * r][tx] = W[(size_t)(td + ty + 8 * r) * D + te + tx];
    __syncthreads();
    ushort_t* o = Wt + (size_t)e * D * D;
    for (int r = 0; r < 4; ++r)
        o[(size_t)(te + ty + 8 * r) * D + td + tx] = f2bf(t[tx][ty + 8 * r]);
}

// ---------------- staging helpers (linear LDS dest, inverse-swizzled src) --
// LDS tile: [256 rows][64 cols] bf16, row stride 128B.
// LDS byte (r*128 + c') holds global byte-col (c' ^ ((r&7)<<4)).
__device__ __forceinline__ void stage_half_A(const ushort_t* __restrict__ Abf,
                                             int brow, int t, ushort_t* dstbuf,
                                             int h, int tid, int wv) {
    #pragma unroll
    for (int i = 0; i < 2; ++i) {
        const int c   = i * 512 + tid;
        const int rr  = c >> 3;
        const int cb  = (c & 7) * 16;
        const int gcb = cb ^ ((rr & 7) << 4);
        const ushort_t* g = Abf + (size_t)(brow + h * 128 + rr) * D + t * 64 + (gcb >> 1);
        ushort_t* l = dstbuf + (h * 16384 + (i * 512 + wv * 64) * 16) / 2;
        load_lds16(g, l);
    }
}

__device__ __forceinline__ void stage_half_B(const ushort_t* __restrict__ Wt,
                                             int bcolIdx, int t, ushort_t* dstbuf,
                                             int h, int tid, int wv) {
    #pragma unroll
    for (int i = 0; i < 2; ++i) {
        const int c   = i * 512 + tid;
        const int rr  = c >> 3;
        const int cb  = (c & 7) * 16;
        const int gcb = cb ^ ((rr & 7) << 4);
        const ushort_t* g = Wt + (size_t)h * D * D
                          + (size_t)(bcolIdx * 128 + rr) * D + t * 64 + (gcb >> 1);
        ushort_t* l = dstbuf + (h * 16384 + (i * 512 + wv * 64) * 16) / 2;
        load_lds16(g, l);
    }
}

#define BAR()   do { __builtin_amdgcn_s_barrier(); __builtin_amdgcn_sched_barrier(0); } while (0)
#define LGKM0() do { asm volatile("s_waitcnt lgkmcnt(0)" ::: "memory"); __builtin_amdgcn_sched_barrier(0); } while (0)
#define VM(N)   do { asm volatile("s_waitcnt vmcnt(" #N ")" ::: "memory"); __builtin_amdgcn_sched_barrier(0); } while (0)
#define PRIO1() __builtin_amdgcn_s_setprio(1)
#define PRIO0() __builtin_amdgcn_s_setprio(0)

// A fragment rows = mh*128 + wr*64 + m*16 + l15  (one half-tile per mh)
#define DS_A(mh)                                                                   \
    do {                                                                           \
        _Pragma("unroll") for (int kk = 0; kk < 2; ++kk)                           \
        _Pragma("unroll") for (int m = 0; m < 4; ++m)                              \
            af[kk][m] = *(const bf16x8*)(curA +                                    \
                (size_t)(((mh) * 128 + wr * 64 + m * 16 + l15) * 128) +            \
                (kk ? x1 : x0));                                                   \
    } while (0)

#define DS_B(E)                                                                    \
    do {                                                                           \
        _Pragma("unroll") for (int kk = 0; kk < 2; ++kk)                           \
        _Pragma("unroll") for (int n = 0; n < 2; ++n)                              \
            bfr[E][kk][n] = *(const bf16x8*)(curB +                                \
                (size_t)(((E) * 128 + wc * 32 + n * 16 + l15) * 128) +             \
                (kk ? x1 : x0));                                                   \
    } while (0)

#define MM(E, mh)                                                                  \
    do {                                                                           \
        _Pragma("unroll") for (int kk = 0; kk < 2; ++kk)                           \
        _Pragma("unroll") for (int m = 0; m < 4; ++m)                              \
        _Pragma("unroll") for (int n = 0; n < 2; ++n)                              \
            acc[E][(mh) * 4 + m][n] = __builtin_amdgcn_mfma_f32_16x16x32_bf16(     \
                af[kk][m], bfr[E][kk][n], acc[E][(mh) * 4 + m][n], 0, 0, 0);       \
    } while (0)

// ---------------- fused dual-expert GEMM, deep-staggered 8-phase ------------
// Block: 256 rows x 128 out-cols x 2 experts. 8 waves = 2M x 4N. BK=64.
// Quadrant order per K-tile u: p1(A0,B0) p2(A0,B1) p3(A1,B1) p4(A1,B0).
// Stage schedule (slot-lifetime-derived, depth >= 4 phases):
//   p1: B(u+1).h0   p2: A(u+1).h1   p3: A(u+2).h0   p4: B(u+2).h1
// Per-phase closing vmcnt(6) keeps <= 3 half-tiles in flight.
__global__ __launch_bounds__(512, 2)
void gemm_dual(const ushort_t* __restrict__ Abf, const ushort_t* __restrict__ Wt,
               const float* __restrict__ bs, const int* __restrict__ idx,
               float* __restrict__ out) {
    constexpr int NT = D / 64;   // 16 K-tiles
    __shared__ __align__(16) ushort_t ldsA[2][256 * 64];   // 64 KB
    __shared__ __align__(16) ushort_t ldsB[2][256 * 64];   // 64 KB

    const int tid  = threadIdx.x;
    const int wv   = tid >> 6;
    const int lane = tid & 63;
    const int wr   = wv >> 2, wc = wv & 3;
    const int l15  = lane & 15, lq = lane >> 4;
    const int swz  = (lane & 7) << 4;
    const int x0   = (lq * 16) ^ swz;
    const int x1   = (64 + lq * 16) ^ swz;

    const int bid     = blockIdx.x;
    const int brow    = (bid >> 3) * 256;
    const int bcolIdx = bid & 7;

    f32x4  acc[2][8][2] = {};
    bf16x8 af[2][4];
    bf16x8 bfr[2][2][2];

    // prologue: 6 half-tiles, oldest-needed first
    stage_half_A(Abf, brow, 0, ldsA[0], 0, tid, wv);   // A0.h0
    stage_half_B(Wt, bcolIdx, 0, ldsB[0], 0, tid, wv); // B0.h0
    stage_half_B(Wt, bcolIdx, 0, ldsB[0], 1, tid, wv); // B0.h1
    stage_half_A(Abf, brow, 0, ldsA[0], 1, tid, wv);   // A0.h1
    stage_half_A(Abf, brow, 1, ldsA[1], 0, tid, wv);   // A1.h0
    stage_half_B(Wt, bcolIdx, 1, ldsB[1], 1, tid, wv); // B1.h1
    VM(8);       // A0.h0, B0.h0 landed
    BAR();

    for (int u = 0; u < NT - 1; ++u) {
        const char* curA = (const char*)ldsA[u & 1];
        const char* curB = (const char*)ldsB[u & 1];

        // ---- p1: (A0,B0); stage B(u+1).h0
        DS_A(0); DS_B(0);
        if (u + 1 < NT) stage_half_B(Wt, bcolIdx, u + 1, ldsB[(u + 1) & 1], 0, tid, wv);
        BAR(); LGKM0();
        PRIO1(); MM(0, 0); PRIO0();
        VM(6); BAR();

        // ---- p2: (A0,B1); stage A(u+1).h1
        DS_B(1);
        if (u + 1 < NT) stage_half_A(Abf, brow, u + 1, ldsA[(u + 1) & 1], 1, tid, wv);
        BAR(); LGKM0();
        PRIO1(); MM(1, 0); PRIO0();
        VM(6); BAR();

        // ---- p3: (A1,B1); stage A(u+2).h0
        DS_A(1);
        if (u + 2 < NT) stage_half_A(Abf, brow, u + 2, ldsA[u & 1], 0, tid, wv);
        BAR(); LGKM0();
        PRIO1(); MM(1, 1); PRIO0();
        VM(6); BAR();

        // ---- p4: (A1,B0) — registers only; stage B(u+2).h1
        if (u + 2 < NT) stage_half_B(Wt, bcolIdx, u + 2, ldsB[u & 1], 1, tid, wv);
        BAR(); LGKM0();
        PRIO1(); MM(0, 1); PRIO0();
        VM(6); BAR();
    }

    // ---- final tile u = NT-1: drain everything once, then 4 wait-free phases
    {
        const char* curA = (const char*)ldsA[(NT - 1) & 1];
        const char* curB = (const char*)ldsB[(NT - 1) & 1];
        VM(0); BAR();

        DS_A(0); DS_B(0);
        BAR(); LGKM0();
        PRIO1(); MM(0, 0); PRIO0();
        BAR();

        DS_B(1);
        BAR(); LGKM0();
        PRIO1(); MM(1, 0); PRIO0();
        BAR();

        DS_A(1);
        BAR(); LGKM0();
        PRIO1(); MM(1, 1); PRIO0();
        BAR();

        LGKM0();
        PRIO1(); MM(0, 1); PRIO0();
    }

    // ---- epilogue: per-expert bias + relu, sum, store f32
    const int i0 = idx[0], i1 = idx[1];
    #pragma unroll
    for (int n = 0; n < 2; ++n) {
        const int col = bcolIdx * 128 + wc * 32 + n * 16 + l15;
        const float b0 = bs[i0 * D + col];
        const float b1 = bs[i1 * D + col];
        #pragma unroll
        for (int mh = 0; mh < 2; ++mh)
        #pragma unroll
        for (int m = 0; m < 4; ++m) {
            const int rbase = brow + mh * 128 + wr * 64 + m * 16 + lq * 4;
            #pragma unroll
            for (int i = 0; i < 4; ++i) {
                float v0 = acc[0][mh * 4 + m][n][i] + b0; v0 = v0 > 0.f ? v0 : 0.f;
                float v1 = acc[1][mh * 4 + m][n][i] + b1; v1 = v1 > 0.f ? v1 : 0.f;
                out[(size_t)(rbase + i) * D + col] = v0 + v1;
            }
        }
    }
}

extern "C" void kernel_launch(void* const* d_in, const int* in_sizes, int n_in,
                              void* d_out, int out_size, void* d_ws, size_t ws_size,
                              hipStream_t stream) {
    const float* x      = (const float*)d_in[0];
    const float* logits = (const float*)d_in[1];
    const float* Ws     = (const float*)d_in[2];
    const float* bs     = (const float*)d_in[3];
    float* out = (float*)d_out;

    char* ws = (char*)d_ws;
    ushort_t* xbf = (ushort_t*)ws;                                   // 16 MB
    ushort_t* Wt  = (ushort_t*)(ws + (size_t)B_ROWS * D * 2);        //  4 MB
    int* idx      = (int*)(ws + (size_t)B_ROWS * D * 2 + (size_t)2 * D * D * 2);

    topk_kernel<<<1, 1, 0, stream>>>(logits, idx);
    convert_x<<<(B_ROWS * D) / (256 * 8), 256, 0, stream>>>(x, xbf);
    gather_transpose_W<<<2 * (D / 32) * (D / 32), 256, 0, stream>>>(Ws, idx, Wt);

    gemm_dual<<<256, 512, 0, stream>>>(xbf, Wt, bs, idx, out);
}

// Round 4
// 55.477 us; speedup vs baseline: 1.0674x; 1.0504x over previous
//
#include <hip/hip_runtime.h>
#include <hip/hip_bf16.h>

#define NUM_OPS 8
#define D 1024
#define B_ROWS 8192

typedef unsigned short ushort_t;
typedef __attribute__((ext_vector_type(8))) short bf16x8;
typedef __attribute__((ext_vector_type(4))) float f32x4;
typedef __attribute__((ext_vector_type(4))) float float4v;
typedef __attribute__((ext_vector_type(8))) unsigned short ushort8;

__device__ __forceinline__ unsigned short f2bf(float f) {
    union { float f; unsigned int u; } v; v.f = f;
    unsigned int u = v.u;
    unsigned int lsb = (u >> 16) & 1u;
    u += 0x7fffu + lsb;   // round-to-nearest-even
    return (unsigned short)(u >> 16);
}

__device__ __forceinline__ void load_lds16(const void* g, void* l) {
    __builtin_amdgcn_global_load_lds(
        (const __attribute__((address_space(1))) void*)g,
        (__attribute__((address_space(3))) void*)l,
        16, 0, 0);
}

// ---------------- top-2 selection ----------------
__global__ void topk_kernel(const float* __restrict__ logits, int* __restrict__ idx) {
    if (threadIdx.x == 0 && blockIdx.x == 0) {
        float best = -__builtin_inff(); int bi = 0;
        for (int i = 0; i < NUM_OPS; ++i) {
            float v = logits[i];
            if (v > best) { best = v; bi = i; }
        }
        float best2 = -__builtin_inff(); int bi2 = 0;
        for (int i = 0; i < NUM_OPS; ++i) {
            if (i == bi) continue;
            float v = logits[i];
            if (v > best2) { best2 = v; bi2 = i; }
        }
        idx[0] = bi; idx[1] = bi2;
    }
}

// ---------------- x : f32 -> bf16 ----------------
__global__ void convert_x(const float* __restrict__ x, ushort_t* __restrict__ xb) {
    int i = (blockIdx.x * 256 + threadIdx.x) * 8;
    float4v v0 = *(const float4v*)(x + i);
    float4v v1 = *(const float4v*)(x + i + 4);
    ushort8 o;
    o[0] = f2bf(v0[0]); o[1] = f2bf(v0[1]); o[2] = f2bf(v0[2]); o[3] = f2bf(v0[3]);
    o[4] = f2bf(v1[0]); o[5] = f2bf(v1[1]); o[6] = f2bf(v1[2]); o[7] = f2bf(v1[3]);
    *(ushort8*)(xb + i) = o;
}

// ------- gather selected experts' W, transpose to [n][k], cast bf16 -------
__global__ void gather_transpose_W(const float* __restrict__ Ws,
                                   const int* __restrict__ idx,
                                   ushort_t* __restrict__ Wt) {
    __shared__ float t[32][33];
    int e    = blockIdx.x >> 10;
    int tile = blockIdx.x & 1023;
    int td = (tile >> 5) << 5;
    int te = (tile & 31) << 5;
    int tx = threadIdx.x & 31, ty = threadIdx.x >> 5;
    const float* W = Ws + (size_t)idx[e] * D * D;
    for (int r = 0; r < 4; ++r)
        t[ty + 8 * r][tx] = W[(size_t)(td + ty + 8 * r) * D + te + tx];
    __syncthreads();
    ushort_t* o = Wt + (size_t)e * D * D;
    for (int r = 0; r < 4; ++r)
        o[(size_t)(te + ty + 8 * r) * D + td + tx] = f2bf(t[tx][ty + 8 * r]);
}

// ---------------- staging helpers (linear LDS dest, inverse-swizzled src) --
// LDS tile: [256 rows][64 cols] bf16, row stride 128B.
// LDS byte (r*128 + c') holds global byte-col (c' ^ ((r&7)<<4)).
__device__ __forceinline__ void stage_half_A(const ushort_t* __restrict__ Abf,
                                             int brow, int t, ushort_t* dstbuf,
                                             int h, int tid, int wv) {
    #pragma unroll
    for (int i = 0; i < 2; ++i) {
        const int c   = i * 512 + tid;
        const int rr  = c >> 3;
        const int cb  = (c & 7) * 16;
        const int gcb = cb ^ ((rr & 7) << 4);
        const ushort_t* g = Abf + (size_t)(brow + h * 128 + rr) * D + t * 64 + (gcb >> 1);
        ushort_t* l = dstbuf + (h * 16384 + (i * 512 + wv * 64) * 16) / 2;
        load_lds16(g, l);
    }
}

__device__ __forceinline__ void stage_half_B(const ushort_t* __restrict__ Wt,
                                             int bcolIdx, int t, ushort_t* dstbuf,
                                             int h, int tid, int wv) {
    #pragma unroll
    for (int i = 0; i < 2; ++i) {
        const int c   = i * 512 + tid;
        const int rr  = c >> 3;
        const int cb  = (c & 7) * 16;
        const int gcb = cb ^ ((rr & 7) << 4);
        const ushort_t* g = Wt + (size_t)h * D * D
                          + (size_t)(bcolIdx * 128 + rr) * D + t * 64 + (gcb >> 1);
        ushort_t* l = dstbuf + (h * 16384 + (i * 512 + wv * 64) * 16) / 2;
        load_lds16(g, l);
    }
}

#define SB()     __builtin_amdgcn_sched_barrier(0)
#define BAR()    do { __builtin_amdgcn_s_barrier(); SB(); } while (0)
#define LGKM(N)  do { asm volatile("s_waitcnt lgkmcnt(" #N ")" ::: "memory"); SB(); } while (0)
#define VM(N)    do { asm volatile("s_waitcnt vmcnt(" #N ")" ::: "memory"); } while (0)
#define PRIO1()  __builtin_amdgcn_s_setprio(1)
#define PRIO0()  __builtin_amdgcn_s_setprio(0)

// ds_read fragments (swizzled addresses). A rows: mh*128 + wr*64 + m*16
#define RD_A(mh)                                                                   \
    do {                                                                           \
        _Pragma("unroll") for (int kk = 0; kk < 2; ++kk)                           \
        _Pragma("unroll") for (int m = 0; m < 4; ++m)                              \
            af[kk][m] = *(const bf16x8*)(curA +                                    \
                (size_t)(((mh) * 128 + wr * 64 + m * 16 + l15) * 128) +            \
                (kk ? x1 : x0));                                                   \
    } while (0)

#define RD_B(E)                                                                    \
    do {                                                                           \
        _Pragma("unroll") for (int kk = 0; kk < 2; ++kk)                           \
        _Pragma("unroll") for (int n = 0; n < 2; ++n)                              \
            bfr[E][kk][n] = *(const bf16x8*)(curB +                                \
                (size_t)(((E) * 128 + wc * 32 + n * 16 + l15) * 128) +             \
                (kk ? x1 : x0));                                                   \
    } while (0)

#define MM(E, mh)                                                                  \
    do {                                                                           \
        _Pragma("unroll") for (int kk = 0; kk < 2; ++kk)                           \
        _Pragma("unroll") for (int m = 0; m < 4; ++m)                              \
        _Pragma("unroll") for (int n = 0; n < 2; ++n)                              \
            acc[E][(mh) * 4 + m][n] = __builtin_amdgcn_mfma_f32_16x16x32_bf16(     \
                af[kk][m], bfr[E][kk][n], acc[E][(mh) * 4 + m][n], 0, 0, 0);       \
    } while (0)

// ---------------- fused dual-expert GEMM: 1 barrier / K-tile ----------------
// Block: 256 rows x 128 out-cols x 2 experts. 8 waves = 2M x 4N. BK=64.
// Per tile: 64 MFMA/wave against ONE exposed drain. Quadrants:
//   q1(A0,B0) q2(A0,B1) q3(A1,B0) q4(A1,B1)  (A regs overwritten after q2)
// All tile-u+1 stage loads issued inside tile u; VM(0) at tail is the
// cross-wave handoff (everything in LDS before BAR). No mid-tile vm waits.
__global__ __launch_bounds__(512, 2)
void gemm_dual(const ushort_t* __restrict__ Abf, const ushort_t* __restrict__ Wt,
               const float* __restrict__ bs, const int* __restrict__ idx,
               float* __restrict__ out) {
    constexpr int NT = D / 64;   // 16 K-tiles
    __shared__ __align__(16) ushort_t ldsA[2][256 * 64];   // 64 KB
    __shared__ __align__(16) ushort_t ldsB[2][256 * 64];   // 64 KB

    const int tid  = threadIdx.x;
    const int wv   = tid >> 6;
    const int lane = tid & 63;
    const int wr   = wv >> 2, wc = wv & 3;
    const int l15  = lane & 15, lq = lane >> 4;
    const int swz  = (lane & 7) << 4;
    const int x0   = (lq * 16) ^ swz;
    const int x1   = (64 + lq * 16) ^ swz;

    // L2-friendly map: consecutive bids = consecutive row panels, same col
    // panel. XCD = bid%8 -> each XCD owns rows {xcd, xcd+8, ...} exclusively
    // (A fetched once chip-wide), B panel (512KB) shared within dispatch window.
    const int bid     = blockIdx.x;
    const int brow    = (bid & 31) * 256;
    const int bcolIdx = bid >> 5;

    f32x4  acc[2][8][2] = {};
    bf16x8 af[2][4];
    bf16x8 bfr[2][2][2];

    // prologue: stage tile 0 (4 halves), drain fully
    stage_half_A(Abf, brow, 0, ldsA[0], 0, tid, wv);
    stage_half_B(Wt, bcolIdx, 0, ldsB[0], 0, tid, wv);
    stage_half_A(Abf, brow, 0, ldsA[0], 1, tid, wv);
    stage_half_B(Wt, bcolIdx, 0, ldsB[0], 1, tid, wv);
    VM(0);

    for (int u = 0; u < NT - 1; ++u) {
        const char* curA = (const char*)ldsA[u & 1];
        const char* curB = (const char*)ldsB[u & 1];
        ushort_t* nA = ldsA[(u & 1) ^ 1];
        ushort_t* nB = ldsB[(u & 1) ^ 1];

        BAR();                 // tile-u data fully in LDS (all waves drained pre-BAR)

        RD_A(0); RD_B(0); RD_B(1);                         // 16 ds_reads
        stage_half_A(Abf, brow, u + 1, nA, 0, tid, wv);    // h0 stages early
        stage_half_B(Wt, bcolIdx, u + 1, nB, 0, tid, wv);

        LGKM(4);               // A0,B0 done; B1 still in flight
        PRIO1(); MM(0, 0); PRIO0();                        // q1

        stage_half_A(Abf, brow, u + 1, nA, 1, tid, wv);

        LGKM(0);               // B1 done (drained under q1 MFMA)
        PRIO1(); MM(1, 0); PRIO0();                        // q2

        RD_A(1);                                           // A regs now dead -> reuse
        stage_half_B(Wt, bcolIdx, u + 1, nB, 1, tid, wv);

        LGKM(0);               // A1 done (drained under q2 tail)
        PRIO1(); MM(0, 1); PRIO0();                        // q3
        PRIO1(); MM(1, 1); PRIO0();                        // q4

        VM(0);                 // all 8 stage loads for tile u+1 landed
    }

    // ---- final tile u = NT-1: no staging
    {
        const char* curA = (const char*)ldsA[(NT - 1) & 1];
        const char* curB = (const char*)ldsB[(NT - 1) & 1];

        BAR();
        RD_A(0); RD_B(0); RD_B(1);
        LGKM(4);
        PRIO1(); MM(0, 0); PRIO0();
        LGKM(0);
        PRIO1(); MM(1, 0); PRIO0();
        RD_A(1);
        LGKM(0);
        PRIO1(); MM(0, 1); PRIO0();
        PRIO1(); MM(1, 1); PRIO0();
    }

    // ---- epilogue: per-expert bias + relu, sum, store f32
    const int i0 = idx[0], i1 = idx[1];
    #pragma unroll
    for (int n = 0; n < 2; ++n) {
        const int col = bcolIdx * 128 + wc * 32 + n * 16 + l15;
        const float b0 = bs[i0 * D + col];
        const float b1 = bs[i1 * D + col];
        #pragma unroll
        for (int mh = 0; mh < 2; ++mh)
        #pragma unroll
        for (int m = 0; m < 4; ++m) {
            const int rbase = brow + mh * 128 + wr * 64 + m * 16 + lq * 4;
            #pragma unroll
            for (int i = 0; i < 4; ++i) {
                float v0 = acc[0][mh * 4 + m][n][i] + b0; v0 = v0 > 0.f ? v0 : 0.f;
                float v1 = acc[1][mh * 4 + m][n][i] + b1; v1 = v1 > 0.f ? v1 : 0.f;
                out[(size_t)(rbase + i) * D + col] = v0 + v1;
            }
        }
    }
}

extern "C" void kernel_launch(void* const* d_in, const int* in_sizes, int n_in,
                              void* d_out, int out_size, void* d_ws, size_t ws_size,
                              hipStream_t stream) {
    const float* x      = (const float*)d_in[0];
    const float* logits = (const float*)d_in[1];
    const float* Ws     = (const float*)d_in[2];
    const float* bs     = (const float*)d_in[3];
    float* out = (float*)d_out;

    char* ws = (char*)d_ws;
    ushort_t* xbf = (ushort_t*)ws;                                   // 16 MB
    ushort_t* Wt  = (ushort_t*)(ws + (size_t)B_ROWS * D * 2);        //  4 MB
    int* idx      = (int*)(ws + (size_t)B_ROWS * D * 2 + (size_t)2 * D * D * 2);

    topk_kernel<<<1, 1, 0, stream>>>(logits, idx);
    convert_x<<<(B_ROWS * D) / (256 * 8), 256, 0, stream>>>(x, xbf);
    gather_transpose_W<<<2 * (D / 32) * (D / 32), 256, 0, stream>>>(Ws, idx, Wt);

    gemm_dual<<<256, 512, 0, stream>>>(xbf, Wt, bs, idx, out);
}